// Round 19
// baseline (40.355 us; speedup 1.0000x reference)
//
#include <hip/hip_runtime.h>
#include <cstdint>

#define B_    2048
#define T_    2048
#define TD    7
#define NCHK  128        // chunks per row (L=16)
#define IDENT 0x4688u    // identity map

__device__ __forceinline__ uint32_t mcompose(uint32_t f, uint32_t g) {
    uint32_t r = 0;
#pragma unroll
    for (int j = 0; j < 5; ++j) {
        uint32_t gj = (g >> (3 * j)) & 7u;
        r |= ((f >> (3 * gj)) & 7u) << (3 * j);
    }
    return r;
}

__device__ __forceinline__ uint32_t cvtpk(float lo, float hi) {
    uint32_t r;
    asm("v_cvt_pk_bf16_f32 %0, %1, %2" : "=v"(r) : "v"(lo), "v"(hi));
    return r;
}

// extract bf16 halfword h from packed dword window
__device__ __forceinline__ float xget(const uint32_t* w, int h) {
    return (h & 1) ? __uint_as_float(w[h >> 1] & 0xFFFF0000u)
                   : __uint_as_float(w[h >> 1] << 16);
}

// uint4 index of group q (0..9) of chunk cc; rotation spreads lanes sharing
// base-mod-32 (c=4k stride) across 8 distinct bank quads -> 2-way max (free)
__device__ __forceinline__ int gidx(int cc, int q) {
    int s = q + ((cc >> 2) & 7);
    s = (s >= 10) ? s - 10 : s;
    return 10 * cc + s;
}

template<bool P>
__device__ __forceinline__ void hstep(const uint32_t* w, int base, bool pred,
                                      float (&dp)[5], const float (&tr)[5][5]) {
    float nd[5];
#pragma unroll
    for (int j = 0; j < 5; ++j) {
        float v = fmaxf(fmaxf(fmaxf(fmaxf(dp[0] + tr[0][j], dp[1] + tr[1][j]),
                                    dp[2] + tr[2][j]), dp[3] + tr[3][j]),
                        dp[4] + tr[4][j]);
        nd[j] = v + xget(w, base + j);
    }
#pragma unroll
    for (int j = 0; j < 5; ++j) dp[j] = (P && !pred) ? dp[j] : nd[j];
}

template<bool SEL>
__device__ __forceinline__ uint32_t lstep(const uint32_t* w, int base, bool mm,
                                          float (&dp)[5], const float (&tr)[5][5],
                                          uint32_t& rho) {
    float nd[5]; int aa[5]; uint32_t pk = 0;
#pragma unroll
    for (int j = 0; j < 5; ++j) {
        float s[5];
#pragma unroll
        for (int i = 0; i < 5; ++i) {
            float f = dp[i] + tr[i][j];
            s[i] = __uint_as_float((__float_as_uint(f) & ~7u) | (uint32_t)(7 - i));
        }
        float m = fmaxf(fmaxf(fmaxf(fmaxf(s[0], s[1]), s[2]), s[3]), s[4]);
        int a = 7 - (int)(__float_as_uint(m) & 7u);
        float v = m + xget(w, base + j);
        if (SEL) { a = mm ? a : j; nd[j] = mm ? v : dp[j]; }
        else     { nd[j] = v; }
        aa[j] = a;
        pk |= ((uint32_t)a) << (3 * j);
    }
    uint32_t nr = 0;
#pragma unroll
    for (int j = 0; j < 5; ++j) nr |= ((rho >> (3 * aa[j])) & 7u) << (3 * j);
    rho = nr;
#pragma unroll
    for (int j = 0; j < 5; ++j) dp[j] = nd[j];
    return pk;
}

__global__ __launch_bounds__(128) void k_all(
    const float* __restrict__ x, const int* __restrict__ mask,
    const float* __restrict__ tf, float* __restrict__ out)
{
    __shared__ __align__(16) uint16_t xs[10240];   // 20480 B EXACT -> 8 blocks/CU
    __shared__ uint32_t tot[2];
    __shared__ float    part[2];
    __shared__ int      lastS;
    uint32_t* xs32 = (uint32_t*)xs;

    const int b = blockIdx.x, c = threadIdx.x;     // c = chunk (L=16), 128 chunks
    const int lane = c & 63, w = c >> 6;

    const float4* gx = (const float4*)(x + (size_t)b * (T_ * 5));

    // ---- stage x: 20 coalesced float4/thread -> bf16 pairs, rotated groups ----
#pragma unroll
    for (int qi = 0; qi < 20; ++qi) {
        int fi = c + 128 * qi;
        float4 v = gx[fi];
        uint32_t e0 = 4u * (uint32_t)fi;           // halfword index in row
        uint32_t co = e0 / 80u;                    // owning chunk (exact magic)
        uint32_t el = e0 - 80u * co;               // halfword within chunk
        uint32_t q  = el >> 3;                     // uint4 group 0..9
        uint32_t s  = q + ((co >> 2) & 7u); s = (s >= 10u) ? s - 10u : s;
        uint32_t dA = 4u * (10u * co + s) + ((el >> 1) & 3u);
        uint2 p; p.x = cvtpk(v.x, v.y); p.y = cvtpk(v.z, v.w);
        *(uint2*)(xs32 + dA) = p;
    }

    // ---- mask: per-lane own chunk (4x int4 = 16 steps) ----
    uint32_t mb = 0;
    {
        const int4* gmc = (const int4*)(mask + (size_t)b * T_ + 16 * c);
        int4 m[4];
#pragma unroll
        for (int u = 0; u < 4; ++u) m[u] = gmc[u];
#pragma unroll
        for (int u = 0; u < 4; ++u) {
            mb |= (m[u].x ? 1u : 0u) << (4 * u);
            mb |= (m[u].y ? 1u : 0u) << (4 * u + 1);
            mb |= (m[u].z ? 1u : 0u) << (4 * u + 2);
            mb |= (m[u].w ? 1u : 0u) << (4 * u + 3);
        }
    }

    float tr[5][5], ts[5], te[5];
#pragma unroll
    for (int i = 0; i < 5; ++i)
#pragma unroll
        for (int j = 0; j < 5; ++j) tr[i][j] = tf[i * TD + j];
#pragma unroll
    for (int j = 0; j < 5; ++j) ts[j] = tf[5 * TD + j];
#pragma unroll
    for (int j = 0; j < 5; ++j) te[j] = tf[j * TD + 6];

    uint32_t mh = __shfl_up(mb, 1);
    if (lane == 0 && w == 1) mh = 0;               // cross-wave halo bits fetched below
    // chunk 64's halo bits come from chunk 63 (other wave) — use LDS via tot? simpler:
    // recompute from global for the single boundary lane:
    if (c == 64) {
        const int4* gp = (const int4*)(mask + (size_t)b * T_ + 16 * 63);
        int4 m2 = gp[2], m3 = gp[3];               // steps 8..15 of chunk 63
        uint32_t hb = 0;
        hb |= (m2.x ? 1u : 0u) << 8;  hb |= (m2.y ? 1u : 0u) << 9;
        hb |= (m2.z ? 1u : 0u) << 10; hb |= (m2.w ? 1u : 0u) << 11;
        hb |= (m3.x ? 1u : 0u) << 12; hb |= (m3.y ? 1u : 0u) << 13;
        hb |= (m3.z ? 1u : 0u) << 14; hb |= (m3.w ? 1u : 0u) << 15;
        mh = hb;
    }
    mh = (c > 0) ? (mh >> 8) : 0u;                 // halo = prev chunk steps 8..15

    const int allm = __syncthreads_and(mb == 0xFFFFu);   // barrier: xs staged + vote

    const uint4* xsv = (const uint4*)xs32;
    const int hc = (c > 0) ? c - 1 : 0;

    // ---- halo H=8: prev chunk groups 5..9 (steps 8..15), 7 warm-up steps ----
    uint32_t hw[20];
#pragma unroll
    for (int k = 0; k < 5; ++k) {
        uint4 t = xsv[gidx(hc, 5 + k)];
        hw[4*k] = t.x; hw[4*k+1] = t.y; hw[4*k+2] = t.z; hw[4*k+3] = t.w;
    }
    float dp[5];
#pragma unroll
    for (int j = 0; j < 5; ++j) dp[j] = xget(hw, j);   // raw init at step 16c-8
    if (allm) {
#pragma unroll
        for (int h = 1; h <= 7; ++h) hstep<false>(hw, 5 * h, true, dp, tr);
    } else {
#pragma unroll
        for (int h = 1; h <= 7; ++h) hstep<true>(hw, 5 * h, ((mh >> h) & 1u) != 0, dp, tr);
    }
    if (c == 0) {                                  // exact t=0 init (live l=0 masked)
        uint4 t0 = xsv[gidx(0, 0)];
        uint32_t w0[4] = { t0.x, t0.y, t0.z, t0.w };
#pragma unroll
        for (int j = 0; j < 5; ++j) dp[j] = xget(w0, j) + ts[j];
    }
    float dpE[5];
#pragma unroll
    for (int j = 0; j < 5; ++j) dpE[j] = (c == 0) ? 0.0f : dp[j];

    // ---- live: 16 exact steps, bp in registers, 2 batches of 5 uint4 ----
    uint32_t acc[8];
    uint32_t rho = IDENT;
#pragma unroll
    for (int bb = 0; bb < 2; ++bb) {
        uint32_t wv[20];
#pragma unroll
        for (int k = 0; k < 5; ++k) {
            uint4 t = xsv[gidx(c, 5 * bb + k)];
            wv[4*k] = t.x; wv[4*k+1] = t.y; wv[4*k+2] = t.z; wv[4*k+3] = t.w;
        }
#pragma unroll
        for (int ll = 0; ll < 8; ++ll) {
            const int l = 8 * bb + ll;
            uint32_t pk;
            if (l == 0) {
                bool mm = (c != 0) && ((mb & 1u) != 0);
                pk = lstep<true>(wv, 0, mm, dp, tr, rho);
            } else if (allm) {
                pk = lstep<false>(wv, 5 * ll, true, dp, tr, rho);
            } else {
                pk = lstep<true>(wv, 5 * ll, ((mb >> l) & 1u) != 0, dp, tr, rho);
            }
            if (l & 1) acc[l >> 1] |= pk << 16;
            else       acc[l >> 1]  = pk;
        }
    }

    // exact per-chunk segment score (within-lane telescoping)
    float svec[5];
#pragma unroll
    for (int j = 0; j < 5; ++j) {
        int r = (rho >> (3 * j)) & 7;
        float e = dpE[0];
        e = (r == 1) ? dpE[1] : e;
        e = (r == 2) ? dpE[2] : e;
        e = (r == 3) ? dpE[3] : e;
        e = (r == 4) ? dpE[4] : e;
        svec[j] = dp[j] - e;
    }

    // ---- suffix composition: intra-wave shfl scan + cross-wave combine ----
    uint32_t I = rho;
#pragma unroll
    for (int d = 1; d < 64; d <<= 1) {
        uint32_t oth = __shfl_down(I, d);
        uint32_t cm  = mcompose(I, oth);
        I = (lane + d < 64) ? cm : I;
    }
    if (lane == 0) tot[w] = I;
    if (c == NCHK - 1) {
        float best = dp[0] + te[0]; int last = 0;
#pragma unroll
        for (int j = 1; j < 5; ++j) {
            float s = dp[j] + te[j];
            if (s > best) { best = s; last = j; }
        }
        lastS = last;
    }
    __syncthreads();

    uint32_t Tw = (w == 0) ? tot[1] : IDENT;
    uint32_t Ex = __shfl_down(I, 1);
    uint32_t M  = (lane < 63) ? mcompose(Ex, Tw) : Tw;
    const int last = lastS;
    const int ec = (int)((M >> (3 * last)) & 7u);

    // ---- exact telescoped score: wave reduce + 2 partials ----
    {
        float v = svec[0];
        v = (ec == 1) ? svec[1] : v;
        v = (ec == 2) ? svec[2] : v;
        v = (ec == 3) ? svec[3] : v;
        v = (ec == 4) ? svec[4] : v;
        if (c == NCHK - 1) v += te[last];
#pragma unroll
        for (int off = 1; off < 64; off <<= 1) v += __shfl_xor(v, off);
        if (lane == 0) part[w] = v;
    }
    __syncthreads();
    if (c == 0) out[b] = part[0] + part[1];

    // ---- path decode from register bp ----
    float pv[16];
    int e = ec;
#pragma unroll
    for (int l = 15; l >= 0; --l) {
        pv[l] = (float)e;
        uint32_t p = (acc[l >> 1] >> (16 * (l & 1))) & 0xFFFFu;
        e = (p >> (3 * e)) & 7;
    }
    float* path = out + B_ + (size_t)b * T_ + 16 * c;
#pragma unroll
    for (int q = 0; q < 4; ++q) {
        float4 v; v.x = pv[4*q]; v.y = pv[4*q+1]; v.z = pv[4*q+2]; v.w = pv[4*q+3];
        ((float4*)path)[q] = v;
    }
}

extern "C" void kernel_launch(void* const* d_in, const int* in_sizes, int n_in,
                              void* d_out, int out_size, void* d_ws, size_t ws_size,
                              hipStream_t stream) {
    const float* x         = (const float*)d_in[0];
    const int*   mask      = (const int*)d_in[1];
    const float* transform = (const float*)d_in[2];
    float*       out       = (float*)d_out;

    hipLaunchKernelGGL(k_all, dim3(B_), dim3(128), 0, stream,
                       x, mask, transform, out);
}

// Round 20
// 34.548 us; speedup vs baseline: 1.1681x; 1.1681x over previous
//
#include <hip/hip_runtime.h>
#include <cstdint>

#define B_    2048
#define T_    2048
#define TD    7
// identity map, byte form: slots 0..3 in lo bytes, slot 4 in hi byte 0
#define ID_LO 0x03020100u
#define ID_HI 0x00000004u

// byte-map compose r = f o g (r[j] = f[g[j]]) : 2x v_perm_b32
// selector byte v: 0..3 -> lo byte v ; 4 -> hi byte 0   (v_perm: 0-3 pick arg2, 4-7 pick arg1)
__device__ __forceinline__ void bcompose(uint32_t fHi, uint32_t fLo,
                                         uint32_t gHi, uint32_t gLo,
                                         uint32_t& rHi, uint32_t& rLo) {
    rLo = __builtin_amdgcn_perm(fHi, fLo, gLo);
    rHi = __builtin_amdgcn_perm(fHi, fLo, gHi);
}

// pack two f32 -> bf16 pair (RNE), low half = first arg
__device__ __forceinline__ uint32_t cvtpk(float lo, float hi) {
    uint32_t r;
    asm("v_cvt_pk_bf16_f32 %0, %1, %2" : "=v"(r) : "v"(lo), "v"(hi));
    return r;
}

// extract bf16 halfword h from packed dword window (h compile-time after unroll)
__device__ __forceinline__ float xget(const uint32_t* w, int h) {
    return (h & 1) ? __uint_as_float(w[h >> 1] & 0xFFFF0000u)
                   : __uint_as_float(w[h >> 1] << 16);
}

// uint4 index of logical group q (0..19) of chunk cc, with per-chunk rotation
__device__ __forceinline__ int gidx(int cc, int q) {
    int s = q + (cc & 7);
    s = (s >= 20) ? s - 20 : s;
    return 20 * cc + s;
}

template<bool P>
__device__ __forceinline__ void hstep(const uint32_t* w, int base, bool pred,
                                      float (&dp)[5], const float (&tr)[5][5]) {
    float nd[5];
#pragma unroll
    for (int j = 0; j < 5; ++j) {
        float v = fmaxf(fmaxf(fmaxf(fmaxf(dp[0] + tr[0][j], dp[1] + tr[1][j]),
                                    dp[2] + tr[2][j]), dp[3] + tr[3][j]),
                        dp[4] + tr[4][j]);
        nd[j] = v + xget(w, base + j);
    }
#pragma unroll
    for (int j = 0; j < 5; ++j) dp[j] = (P && !pred) ? dp[j] : nd[j];
}

// live step: mantissa-embedded argmax; rho maintained in byte form via v_perm
template<bool SEL>
__device__ __forceinline__ uint32_t lstep(const uint32_t* w, int base, bool mm,
                                          float (&dp)[5], const float (&tr)[5][5],
                                          uint32_t& rHi, uint32_t& rLo) {
    float nd[5]; int aa[5]; uint32_t pk = 0;
#pragma unroll
    for (int j = 0; j < 5; ++j) {
        float s[5];
#pragma unroll
        for (int i = 0; i < 5; ++i) {
            float f = dp[i] + tr[i][j];
            s[i] = __uint_as_float((__float_as_uint(f) & ~7u) | (uint32_t)(7 - i));
        }
        float m = fmaxf(fmaxf(fmaxf(fmaxf(s[0], s[1]), s[2]), s[3]), s[4]); // 2x v_max3
        int a = 7 - (int)(__float_as_uint(m) & 7u);
        float v = m + xget(w, base + j);
        if (SEL) { a = mm ? a : j; nd[j] = mm ? v : dp[j]; }
        else     { nd[j] = v; }
        aa[j] = a;
        pk |= ((uint32_t)a) << (3 * j);
    }
    // byte-form selector + 2-perm compose: rho = rho o pk
    uint32_t pLo = (uint32_t)aa[0] | ((uint32_t)aa[1] << 8) |
                   ((uint32_t)aa[2] << 16) | ((uint32_t)aa[3] << 24);
    uint32_t pHi = (uint32_t)aa[4];
    uint32_t nLo, nHi;
    bcompose(rHi, rLo, pHi, pLo, nHi, nLo);
    rLo = nLo; rHi = nHi;
#pragma unroll
    for (int j = 0; j < 5; ++j) dp[j] = nd[j];
    return pk;
}

__global__ __launch_bounds__(64) void k_all(
    const float* __restrict__ x, const int* __restrict__ mask,
    const float* __restrict__ tf, float* __restrict__ out)
{
    __shared__ __align__(16) uint16_t xs[10240];   // 20480 B EXACT -> 8 blocks/CU
    const int b = blockIdx.x, c = threadIdx.x;     // c = chunk (L=32), 64 chunks

    const float4* gx = (const float4*)(x + (size_t)b * (T_ * 5));
    const int*    gi = mask + (size_t)b * T_;

    // ---- stage x: 40 coalesced float4/thread -> bf16 pairs, rotated groups ----
#pragma unroll
    for (int qi = 0; qi < 40; ++qi) {
        int fi = c + 64 * qi;
        float4 v = gx[fi];
        uint32_t e0 = 4u * (uint32_t)fi;
        uint32_t co = e0 / 160u;                 // owning chunk (exact)
        uint32_t el = e0 - 160u * co;
        uint32_t q  = el >> 3;
        uint32_t s  = q + (co & 7u); s = (s >= 20u) ? s - 20u : s;
        uint32_t ha = 160u * co + 8u * s + (el & 7u);
        uint2 p; p.x = cvtpk(v.x, v.y); p.y = cvtpk(v.z, v.w);
        *(uint2*)(xs + ha) = p;
    }

    // ---- mask: coalesced dword loads + ballot pack (32 bits per chunk) ----
    uint32_t mb = 0;
    {
        int mv[32];
#pragma unroll
        for (int q = 0; q < 32; ++q) mv[q] = gi[c + 64 * q];
#pragma unroll
        for (int q = 0; q < 32; ++q) {
            unsigned long long bal = __ballot(mv[q] != 0);
            if (c == 2 * q)     mb = (uint32_t)bal;
            if (c == 2 * q + 1) mb = (uint32_t)(bal >> 32);
        }
    }

    float tr[5][5], ts[5], te[5];
#pragma unroll
    for (int i = 0; i < 5; ++i)
#pragma unroll
        for (int j = 0; j < 5; ++j) tr[i][j] = tf[i * TD + j];
#pragma unroll
    for (int j = 0; j < 5; ++j) ts[j] = tf[5 * TD + j];
#pragma unroll
    for (int j = 0; j < 5; ++j) te[j] = tf[j * TD + 6];

    const bool allm = __all(mb == 0xFFFFFFFFu);
    uint32_t mh = __shfl_up(mb, 1);
    mh = (c > 0) ? (mh >> 24) : 0u;              // halo bits = prev chunk steps 24..31

    __syncthreads();                             // xs staged

    const uint4* xsv = (const uint4*)xs;
    const int hc = (c > 0) ? c - 1 : 0;

    // ---- halo H=8: prev chunk groups 15..19 (steps 24..31), 7 warm-up steps ----
    uint32_t hw[20];
#pragma unroll
    for (int k = 0; k < 5; ++k) {
        uint4 t = xsv[gidx(hc, 15 + k)];
        hw[4*k] = t.x; hw[4*k+1] = t.y; hw[4*k+2] = t.z; hw[4*k+3] = t.w;
    }
    float dp[5];
#pragma unroll
    for (int j = 0; j < 5; ++j) dp[j] = xget(hw, j);   // raw init at step 32c-8
    if (allm) {
#pragma unroll
        for (int h = 1; h <= 7; ++h) hstep<false>(hw, 5 * h, true, dp, tr);
    } else {
#pragma unroll
        for (int h = 1; h <= 7; ++h) hstep<true>(hw, 5 * h, ((mh >> h) & 1u) != 0, dp, tr);
    }
    if (c == 0) {                                // exact t=0 init (live l=0 masked)
        uint4 t0 = xsv[gidx(0, 0)];
        uint32_t w0[4] = { t0.x, t0.y, t0.z, t0.w };
#pragma unroll
        for (int j = 0; j < 5; ++j) dp[j] = xget(w0, j) + ts[j];
    }
    float dpE[5];
#pragma unroll
    for (int j = 0; j < 5; ++j) dpE[j] = (c == 0) ? 0.0f : dp[j];

    // ---- live: 32 exact steps, bp in registers, rho in byte form ----
    uint32_t acc[16];
    uint32_t rLo = ID_LO, rHi = ID_HI;
#pragma unroll
    for (int bb = 0; bb < 4; ++bb) {
        uint32_t w[20];
#pragma unroll
        for (int k = 0; k < 5; ++k) {
            uint4 t = xsv[gidx(c, 5 * bb + k)];
            w[4*k] = t.x; w[4*k+1] = t.y; w[4*k+2] = t.z; w[4*k+3] = t.w;
        }
#pragma unroll
        for (int ll = 0; ll < 8; ++ll) {
            const int l = 8 * bb + ll;
            uint32_t pk;
            if (l == 0) {
                bool mm = (c != 0) && ((mb & 1u) != 0);
                pk = lstep<true>(w, 0, mm, dp, tr, rHi, rLo);
            } else if (allm) {
                pk = lstep<false>(w, 5 * ll, true, dp, tr, rHi, rLo);
            } else {
                pk = lstep<true>(w, 5 * ll, ((mb >> l) & 1u) != 0, dp, tr, rHi, rLo);
            }
            if (l & 1) acc[l >> 1] |= pk << 16;
            else       acc[l >> 1]  = pk;
        }
    }

    // exact per-chunk segment score of decoded tree (within-lane telescoping)
    float svec[5];
#pragma unroll
    for (int j = 0; j < 5; ++j) {
        int r = (j < 4) ? (int)((rLo >> (8 * j)) & 0xFFu) : (int)(rHi & 0xFFu);
        float e = dpE[0];
        e = (r == 1) ? dpE[1] : e;
        e = (r == 2) ? dpE[2] : e;
        e = (r == 3) ? dpE[3] : e;
        e = (r == 4) ? dpE[4] : e;
        svec[j] = dp[j] - e;
    }

    // ---- wave-local suffix composition over 64 chunks (byte form) ----
    uint32_t iLo = rLo, iHi = rHi;
#pragma unroll
    for (int d = 1; d < 64; d <<= 1) {
        uint32_t oLo = __shfl_down(iLo, d);
        uint32_t oHi = __shfl_down(iHi, d);
        uint32_t cLo, cHi;
        bcompose(iHi, iLo, oHi, oLo, cHi, cLo);
        bool ok = (c + d < 64);
        iLo = ok ? cLo : iLo;
        iHi = ok ? cHi : iHi;
    }
    float best = dp[0] + te[0]; int lastv = 0;
#pragma unroll
    for (int j = 1; j < 5; ++j) {
        float s = dp[j] + te[j];
        if (s > best) { best = s; lastv = j; }
    }
    const int last = __shfl(lastv, 63);
    uint32_t MLo = __shfl_down(iLo, 1);
    uint32_t MHi = __shfl_down(iHi, 1);
    if (c == 63) { MLo = ID_LO; MHi = ID_HI; }
    const int ec = (int)(__builtin_amdgcn_perm(MHi, MLo, (uint32_t)last) & 0xFFu);

    // ---- exact telescoped score: wave reduce ----
    {
        float v = svec[0];
        v = (ec == 1) ? svec[1] : v;
        v = (ec == 2) ? svec[2] : v;
        v = (ec == 3) ? svec[3] : v;
        v = (ec == 4) ? svec[4] : v;
        if (c == 63) v += te[last];
#pragma unroll
        for (int off = 1; off < 64; off <<= 1) v += __shfl_xor(v, off);
        if (c == 0) out[b] = v;
    }

    // ---- path decode from register bp ----
    float pv[32];
    int e = ec;
#pragma unroll
    for (int l = 31; l >= 0; --l) {
        pv[l] = (float)e;
        uint32_t p = (acc[l >> 1] >> (16 * (l & 1))) & 0xFFFFu;
        e = (p >> (3 * e)) & 7;
    }
    float* path = out + B_ + (size_t)b * T_ + c * 32;
#pragma unroll
    for (int q = 0; q < 8; ++q) {
        float4 v; v.x = pv[4*q]; v.y = pv[4*q+1]; v.z = pv[4*q+2]; v.w = pv[4*q+3];
        ((float4*)path)[q] = v;
    }
}

extern "C" void kernel_launch(void* const* d_in, const int* in_sizes, int n_in,
                              void* d_out, int out_size, void* d_ws, size_t ws_size,
                              hipStream_t stream) {
    const float* x         = (const float*)d_in[0];
    const int*   mask      = (const int*)d_in[1];
    const float* transform = (const float*)d_in[2];
    float*       out       = (float*)d_out;

    hipLaunchKernelGGL(k_all, dim3(B_), dim3(64), 0, stream,
                       x, mask, transform, out);
}

// Round 21
// 33.733 us; speedup vs baseline: 1.1963x; 1.0242x over previous
//
#include <hip/hip_runtime.h>
#include <cstdint>

#define B_    2048
#define T_    2048
#define TD    7
// identity map, byte form: slots 0..3 in lo bytes, slot 4 in hi byte 0
#define ID_LO 0x03020100u
#define ID_HI 0x00000004u

// byte-map compose r = f o g (r[j] = f[g[j]]) : 2x v_perm_b32
__device__ __forceinline__ void bcompose(uint32_t fHi, uint32_t fLo,
                                         uint32_t gHi, uint32_t gLo,
                                         uint32_t& rHi, uint32_t& rLo) {
    rLo = __builtin_amdgcn_perm(fHi, fLo, gLo);
    rHi = __builtin_amdgcn_perm(fHi, fLo, gHi);
}

// pack two f32 -> bf16 pair (RNE), low half = first arg
__device__ __forceinline__ uint32_t cvtpk(float lo, float hi) {
    uint32_t r;
    asm("v_cvt_pk_bf16_f32 %0, %1, %2" : "=v"(r) : "v"(lo), "v"(hi));
    return r;
}

// extract bf16 halfword h from packed dword window (h compile-time after unroll)
__device__ __forceinline__ float xget(const uint32_t* w, int h) {
    return (h & 1) ? __uint_as_float(w[h >> 1] & 0xFFFF0000u)
                   : __uint_as_float(w[h >> 1] << 16);
}

// uint4 index of logical group q (0..19) of chunk cc, with per-chunk rotation
__device__ __forceinline__ int gidx(int cc, int q) {
    int s = q + (cc & 7);
    s = (s >= 20) ? s - 20 : s;
    return 20 * cc + s;
}

template<bool P>
__device__ __forceinline__ void hstep(const uint32_t* w, int base, bool pred,
                                      float (&dp)[5], const float (&tr)[5][5]) {
    float nd[5];
#pragma unroll
    for (int j = 0; j < 5; ++j) {
        float v = fmaxf(fmaxf(fmaxf(fmaxf(dp[0] + tr[0][j], dp[1] + tr[1][j]),
                                    dp[2] + tr[2][j]), dp[3] + tr[3][j]),
                        dp[4] + tr[4][j]);
        nd[j] = v + xget(w, base + j);
    }
#pragma unroll
    for (int j = 0; j < 5; ++j) dp[j] = (P && !pred) ? dp[j] : nd[j];
}

// live step: mantissa-embedded argmax (tag = i); rho in byte form via v_perm
template<bool SEL>
__device__ __forceinline__ uint32_t lstep(const uint32_t* w, int base, bool mm,
                                          float (&dp)[5], const float (&tr)[5][5],
                                          uint32_t& rHi, uint32_t& rLo) {
    float nd[5]; int aa[5]; uint32_t pk = 0;
#pragma unroll
    for (int j = 0; j < 5; ++j) {
        float s[5];
#pragma unroll
        for (int i = 0; i < 5; ++i) {
            float f = dp[i] + tr[i][j];
            s[i] = __uint_as_float((__float_as_uint(f) & ~7u) | (uint32_t)i); // v_and_or
        }
        float m = fmaxf(fmaxf(fmaxf(fmaxf(s[0], s[1]), s[2]), s[3]), s[4]); // 2x v_max3
        int a = (int)(__float_as_uint(m) & 7u);    // tag = i -> direct extract
        float v = m + xget(w, base + j);
        if (SEL) { a = mm ? a : j; nd[j] = mm ? v : dp[j]; }
        else     { nd[j] = v; }
        aa[j] = a;
        pk |= ((uint32_t)a) << (3 * j);
    }
    uint32_t pLo = (uint32_t)aa[0] | ((uint32_t)aa[1] << 8) |
                   ((uint32_t)aa[2] << 16) | ((uint32_t)aa[3] << 24);
    uint32_t pHi = (uint32_t)aa[4];
    uint32_t nLo, nHi;
    bcompose(rHi, rLo, pHi, pLo, nHi, nLo);
    rLo = nLo; rHi = nHi;
#pragma unroll
    for (int j = 0; j < 5; ++j) dp[j] = nd[j];
    return pk;
}

__global__ __launch_bounds__(64) void k_all(
    const float* __restrict__ x, const int* __restrict__ mask,
    const float* __restrict__ tf, float* __restrict__ out)
{
    __shared__ __align__(16) uint16_t xs[10240];   // 20480 B EXACT -> 8 blocks/CU
    const int b = blockIdx.x, c = threadIdx.x;     // c = chunk (L=32), 64 chunks

    const float4* gx = (const float4*)(x + (size_t)b * (T_ * 5));
    const int*    gi = mask + (size_t)b * T_;

    // ---- stage x: 40 coalesced float4/thread -> bf16 pairs, rotated groups ----
#pragma unroll
    for (int qi = 0; qi < 40; ++qi) {
        int fi = c + 64 * qi;
        float4 v = gx[fi];
        uint32_t e0 = 4u * (uint32_t)fi;
        uint32_t co = e0 / 160u;                 // owning chunk (exact)
        uint32_t el = e0 - 160u * co;
        uint32_t q  = el >> 3;
        uint32_t s  = q + (co & 7u); s = (s >= 20u) ? s - 20u : s;
        uint32_t ha = 160u * co + 8u * s + (el & 7u);
        uint2 p; p.x = cvtpk(v.x, v.y); p.y = cvtpk(v.z, v.w);
        *(uint2*)(xs + ha) = p;
    }

    // ---- mask: coalesced dword loads + ballot pack (32 bits per chunk) ----
    uint32_t mb = 0;
    {
        int mv[32];
#pragma unroll
        for (int q = 0; q < 32; ++q) mv[q] = gi[c + 64 * q];
#pragma unroll
        for (int q = 0; q < 32; ++q) {
            unsigned long long bal = __ballot(mv[q] != 0);
            if (c == 2 * q)     mb = (uint32_t)bal;
            if (c == 2 * q + 1) mb = (uint32_t)(bal >> 32);
        }
    }

    float tr[5][5], ts[5], te[5];
#pragma unroll
    for (int i = 0; i < 5; ++i)
#pragma unroll
        for (int j = 0; j < 5; ++j) tr[i][j] = tf[i * TD + j];
#pragma unroll
    for (int j = 0; j < 5; ++j) ts[j] = tf[5 * TD + j];
#pragma unroll
    for (int j = 0; j < 5; ++j) te[j] = tf[j * TD + 6];

    const bool allm = __all(mb == 0xFFFFFFFFu);
    uint32_t mh = __shfl_up(mb, 1);
    mh = (c > 0) ? (mh >> 28) : 0u;              // halo bits: prev steps 28..31

    __syncthreads();                             // xs staged

    const uint4* xsv = (const uint4*)xs;
    const int hc = (c > 0) ? c - 1 : 0;

    // ---- halo H=4: prev chunk groups 17..19 (el 136..159), 3 warm-up steps ----
    uint32_t hw[12];
#pragma unroll
    for (int k = 0; k < 3; ++k) {
        uint4 t = xsv[gidx(hc, 17 + k)];
        hw[4*k] = t.x; hw[4*k+1] = t.y; hw[4*k+2] = t.z; hw[4*k+3] = t.w;
    }
    float dp[5];
#pragma unroll
    for (int j = 0; j < 5; ++j) dp[j] = xget(hw, 4 + j);   // init at step 32c-4
    if (allm) {
#pragma unroll
        for (int h = 1; h <= 3; ++h) hstep<false>(hw, 4 + 5 * h, true, dp, tr);
    } else {
#pragma unroll
        for (int h = 1; h <= 3; ++h) hstep<true>(hw, 4 + 5 * h, ((mh >> h) & 1u) != 0, dp, tr);
    }
    if (c == 0) {                                // exact t=0 init (live l=0 masked)
        uint4 t0 = xsv[gidx(0, 0)];
        uint32_t w0[4] = { t0.x, t0.y, t0.z, t0.w };
#pragma unroll
        for (int j = 0; j < 5; ++j) dp[j] = xget(w0, j) + ts[j];
    }
    float dpE[5];
#pragma unroll
    for (int j = 0; j < 5; ++j) dpE[j] = (c == 0) ? 0.0f : dp[j];

    // ---- live: 32 exact steps, bp in registers, rho in byte form ----
    uint32_t acc[16];
    uint32_t rLo = ID_LO, rHi = ID_HI;
#pragma unroll
    for (int bb = 0; bb < 4; ++bb) {
        uint32_t w[20];
#pragma unroll
        for (int k = 0; k < 5; ++k) {
            uint4 t = xsv[gidx(c, 5 * bb + k)];
            w[4*k] = t.x; w[4*k+1] = t.y; w[4*k+2] = t.z; w[4*k+3] = t.w;
        }
#pragma unroll
        for (int ll = 0; ll < 8; ++ll) {
            const int l = 8 * bb + ll;
            uint32_t pk;
            if (l == 0) {
                bool mm = (c != 0) && ((mb & 1u) != 0);
                pk = lstep<true>(w, 0, mm, dp, tr, rHi, rLo);
            } else if (allm) {
                pk = lstep<false>(w, 5 * ll, true, dp, tr, rHi, rLo);
            } else {
                pk = lstep<true>(w, 5 * ll, ((mb >> l) & 1u) != 0, dp, tr, rHi, rLo);
            }
            if (l & 1) acc[l >> 1] |= pk << 16;
            else       acc[l >> 1]  = pk;
        }
    }

    // exact per-chunk segment score of decoded tree (within-lane telescoping)
    float svec[5];
#pragma unroll
    for (int j = 0; j < 5; ++j) {
        int r = (j < 4) ? (int)((rLo >> (8 * j)) & 0xFFu) : (int)(rHi & 0xFFu);
        float e = dpE[0];
        e = (r == 1) ? dpE[1] : e;
        e = (r == 2) ? dpE[2] : e;
        e = (r == 3) ? dpE[3] : e;
        e = (r == 4) ? dpE[4] : e;
        svec[j] = dp[j] - e;
    }

    // ---- wave-local suffix composition over 64 chunks (byte form) ----
    uint32_t iLo = rLo, iHi = rHi;
#pragma unroll
    for (int d = 1; d < 64; d <<= 1) {
        uint32_t oLo = __shfl_down(iLo, d);
        uint32_t oHi = __shfl_down(iHi, d);
        uint32_t cLo, cHi;
        bcompose(iHi, iLo, oHi, oLo, cHi, cLo);
        bool ok = (c + d < 64);
        iLo = ok ? cLo : iLo;
        iHi = ok ? cHi : iHi;
    }
    float best = dp[0] + te[0]; int lastv = 0;
#pragma unroll
    for (int j = 1; j < 5; ++j) {
        float s = dp[j] + te[j];
        if (s > best) { best = s; lastv = j; }
    }
    const int last = __shfl(lastv, 63);
    uint32_t MLo = __shfl_down(iLo, 1);
    uint32_t MHi = __shfl_down(iHi, 1);
    if (c == 63) { MLo = ID_LO; MHi = ID_HI; }
    const int ec = (int)(__builtin_amdgcn_perm(MHi, MLo, (uint32_t)last) & 0xFFu);

    // ---- exact telescoped score: wave reduce ----
    {
        float v = svec[0];
        v = (ec == 1) ? svec[1] : v;
        v = (ec == 2) ? svec[2] : v;
        v = (ec == 3) ? svec[3] : v;
        v = (ec == 4) ? svec[4] : v;
        if (c == 63) v += te[last];
#pragma unroll
        for (int off = 1; off < 64; off <<= 1) v += __shfl_xor(v, off);
        if (c == 0) out[b] = v;
    }

    // ---- path decode from register bp ----
    float pv[32];
    int e = ec;
#pragma unroll
    for (int l = 31; l >= 0; --l) {
        pv[l] = (float)e;
        uint32_t p = (acc[l >> 1] >> (16 * (l & 1))) & 0xFFFFu;
        e = (p >> (3 * e)) & 7;
    }
    float* path = out + B_ + (size_t)b * T_ + c * 32;
#pragma unroll
    for (int q = 0; q < 8; ++q) {
        float4 v; v.x = pv[4*q]; v.y = pv[4*q+1]; v.z = pv[4*q+2]; v.w = pv[4*q+3];
        ((float4*)path)[q] = v;
    }
}

extern "C" void kernel_launch(void* const* d_in, const int* in_sizes, int n_in,
                              void* d_out, int out_size, void* d_ws, size_t ws_size,
                              hipStream_t stream) {
    const float* x         = (const float*)d_in[0];
    const int*   mask      = (const int*)d_in[1];
    const float* transform = (const float*)d_in[2];
    float*       out       = (float*)d_out;

    hipLaunchKernelGGL(k_all, dim3(B_), dim3(64), 0, stream,
                       x, mask, transform, out);
}